// Round 1
// baseline (493.294 us; speedup 1.0000x reference)
//
#include <hip/hip_runtime.h>
#include <hip/hip_fp16.h>
#include <float.h>

#define MKEY 256        // K (key size)
#define NMEM 100000     // memory rows
#define NPAD 100096     // 391 * 256
#define NQ   2048       // queries
#define NTILES 782      // 128-row screening granularity for bmaxT (rescore unchanged)
#define NT256 391       // 256-row GEMM tiles (NPAD / 256)
#define GRID2 (8 * 392) // 8 mtiles x padded ntile space; nt>=391 early-exits
#define KEYBLOCKS (NPAD / 4)   // 25024

typedef _Float16 f16x8 __attribute__((ext_vector_type(8)));
typedef float f32x4 __attribute__((ext_vector_type(4)));

__device__ inline void gll16(const void* g, void* l) {
  __builtin_amdgcn_global_load_lds(
      (const __attribute__((address_space(1))) unsigned*)g,
      (__attribute__((address_space(3))) unsigned*)l, 16, 0, 0);
}

// merged: keys fp32 -> fp16 + inv key norm (blocks 0..25023); query fp32 -> fp16
__global__ void convert(const float* __restrict__ q, const float* __restrict__ mem,
                        unsigned short* __restrict__ qh, unsigned short* __restrict__ kh,
                        float* __restrict__ rkn) {
  const int b = blockIdx.x;
  if (b >= KEYBLOCKS) {
    const int i = (b - KEYBLOCKS) * 256 + threadIdx.x;
    qh[i] = __half_as_ushort(__float2half(q[i]));
    return;
  }
  const int t = threadIdx.x, lane = t & 63, w = t >> 6;
  const int row = b * 4 + w;
  if (row < NMEM) {
    const float4 v = *(const float4*)&mem[(long)row * 512 + lane * 4];
    float fs[4] = {v.x, v.y, v.z, v.w};
    unsigned short hb[4];
    float ss = 0.f;
#pragma unroll
    for (int c = 0; c < 4; ++c) {
      ss += fs[c] * fs[c];
      hb[c] = __half_as_ushort(__float2half(fs[c]));
    }
    *(ushort4*)&kh[(long)row * 256 + lane * 4] = make_ushort4(hb[0], hb[1], hb[2], hb[3]);
#pragma unroll
    for (int off = 32; off >= 1; off >>= 1) ss += __shfl_xor(ss, off, 64);
    if (lane == 0) rkn[row] = 1.0f / sqrtf(fmaxf(ss, 1e-30f));
  } else {
    *(ushort4*)&kh[(long)row * 256 + lane * 4] = make_ushort4(0, 0, 0, 0);
    if (lane == 0) rkn[row] = 0.f;
  }
}

// Pass 1: fp16 screening GEMM, 256x256 tile, BK=64, 8 waves, 8-phase pipelined
// schedule (T2 swizzle + T3/T4 counted vmcnt + T5 setprio). Writes per-(query,
// 128-key-group) max score transposed: bmaxT[group * NQ + query].
__global__ __launch_bounds__(512, 2) void gemm_screen(
    const unsigned short* __restrict__ qh, const unsigned short* __restrict__ kh,
    const float* __restrict__ rkn, float* __restrict__ bmaxT) {
  // LDS 128KB: buf b at b*65536; within buf: A half0 [0,16K) A half1 [16K,32K)
  //            B half0 [32K,48K) B half1 [48K,64K). half = 128 rows x 64 f16.
  __shared__ __align__(128) char smem[131072];

  const int id = blockIdx.x;
  const int mt = (id >> 3) & 7;              // same-nt blocks share an XCD
  const int nt = (id & 7) + 8 * (id >> 6);
  if (nt >= NT256) return;

  const int t = threadIdx.x;
  const int w = t >> 6, lane = t & 63;
  const int wr = w >> 2, wc = w & 3;         // 2x4 wave grid, per-wave 128x64
  const int l16 = lane & 15, q16 = lane >> 4;
  const int l8 = lane >> 3, c8 = lane & 7;

  // staging: LDS physical chunk (rh, cp) holds global chunk cp ^ (rh & 7).
  // gll16 dest = wave-uniform base + lane*16 (linear), so the swizzle is
  // pre-applied to the per-lane GLOBAL source (rule #21).
  const int swz = (c8 ^ l8) * 16;
  const int soff0 = ((0 * 8 + w) * 8 + l8) * 512 + swz;
  const int soff1 = ((1 * 8 + w) * 8 + l8) * 512 + swz;
  const int ldst0 = (0 * 8 + w) * 1024;
  const int ldst1 = (1 * 8 + w) * 1024;
  const char* const aSrc = (const char*)qh + (size_t)mt * 256 * 512;
  const char* const bSrc = (const char*)kh + (size_t)nt * 256 * 512;

#define STAGE(buf, half, kt)                                                        \
  do {                                                                              \
    const char* _s = (((half) < 2) ? aSrc : bSrc) + ((half) & 1) * 65536 + (kt) * 128; \
    char* _d = smem + (buf) * 65536 + (half) * 16384;                               \
    gll16(_s + soff0, _d + ldst0);                                                  \
    gll16(_s + soff1, _d + ldst1);                                                  \
  } while (0)

  // ds_read addresses: logical chunk cl = ks*4+q16, physical cp = cl ^ (l16&7)
  int aoff[2], boff[2];
#pragma unroll
  for (int ks = 0; ks < 2; ++ks) {
    const int pc = ((ks * 4 + q16) ^ (l16 & 7)) * 16;
    aoff[ks] = l16 * 128 + pc;
    boff[ks] = (wc & 1) * 8192 + l16 * 128 + pc;
  }

  f32x4 acc[8][4];
#pragma unroll
  for (int i = 0; i < 8; ++i)
#pragma unroll
    for (int j = 0; j < 4; ++j) acc[i][j] = (f32x4){0.f, 0.f, 0.f, 0.f};

  // prologue: K0 all 4 halves + K1.h0; wait K0 landed (K1.h0 stays in flight)
  STAGE(0, 0, 0); STAGE(0, 1, 0); STAGE(0, 2, 0); STAGE(0, 3, 0);
  STAGE(1, 0, 1);
  asm volatile("s_waitcnt vmcnt(2)" ::: "memory");
  __builtin_amdgcn_s_barrier();

  f16x8 af[4][2], bf[4][2];

#pragma unroll
  for (int kt = 0; kt < 4; ++kt) {
    const int bs = kt & 1;
    const char* ab = smem + bs * 65536 + wr * 16384;
    const char* bb = smem + bs * 65536 + 32768 + (wc >> 1) * 16384;

    // ---- phase 0: ds A(m0-3)+B(n0-1); stage (kt+1).A1 ----
#pragma unroll
    for (int m = 0; m < 4; ++m)
#pragma unroll
      for (int ks = 0; ks < 2; ++ks)
        af[m][ks] = *(const f16x8*)(ab + m * 2048 + aoff[ks]);
#pragma unroll
    for (int j = 0; j < 2; ++j)
#pragma unroll
      for (int ks = 0; ks < 2; ++ks)
        bf[j][ks] = *(const f16x8*)(bb + j * 2048 + boff[ks]);
    if (kt < 3) STAGE(bs ^ 1, 1, kt + 1);
    __builtin_amdgcn_s_barrier();
    asm volatile("s_waitcnt lgkmcnt(0)" ::: "memory");
    __builtin_amdgcn_sched_barrier(0);
    __builtin_amdgcn_s_setprio(1);
#pragma unroll
    for (int m = 0; m < 4; ++m)
#pragma unroll
      for (int j = 0; j < 2; ++j)
#pragma unroll
        for (int ks = 0; ks < 2; ++ks)
          acc[m][j] = __builtin_amdgcn_mfma_f32_16x16x32_f16(af[m][ks], bf[j][ks], acc[m][j], 0, 0, 0);
    __builtin_amdgcn_s_setprio(0);
    __builtin_amdgcn_s_barrier();

    // ---- phase 1: ds B(n2-3); stage (kt+1).B0 ----
#pragma unroll
    for (int j = 2; j < 4; ++j)
#pragma unroll
      for (int ks = 0; ks < 2; ++ks)
        bf[j][ks] = *(const f16x8*)(bb + j * 2048 + boff[ks]);
    if (kt < 3) STAGE(bs ^ 1, 2, kt + 1);
    __builtin_amdgcn_s_barrier();
    asm volatile("s_waitcnt lgkmcnt(0)" ::: "memory");
    __builtin_amdgcn_sched_barrier(0);
    __builtin_amdgcn_s_setprio(1);
#pragma unroll
    for (int m = 0; m < 4; ++m)
#pragma unroll
      for (int j = 2; j < 4; ++j)
#pragma unroll
        for (int ks = 0; ks < 2; ++ks)
          acc[m][j] = __builtin_amdgcn_mfma_f32_16x16x32_f16(af[m][ks], bf[j][ks], acc[m][j], 0, 0, 0);
    __builtin_amdgcn_s_setprio(0);
    __builtin_amdgcn_s_barrier();

    // ---- phase 2: ds A(m4-7) (reuse af); stage (kt+1).B1 ----
#pragma unroll
    for (int m = 0; m < 4; ++m)
#pragma unroll
      for (int ks = 0; ks < 2; ++ks)
        af[m][ks] = *(const f16x8*)(ab + (m + 4) * 2048 + aoff[ks]);
    if (kt < 3) STAGE(bs ^ 1, 3, kt + 1);
    __builtin_amdgcn_s_barrier();
    asm volatile("s_waitcnt lgkmcnt(0)" ::: "memory");
    __builtin_amdgcn_sched_barrier(0);
    __builtin_amdgcn_s_setprio(1);
#pragma unroll
    for (int m = 0; m < 4; ++m)
#pragma unroll
      for (int j = 0; j < 2; ++j)
#pragma unroll
        for (int ks = 0; ks < 2; ++ks)
          acc[m + 4][j] = __builtin_amdgcn_mfma_f32_16x16x32_f16(af[m][ks], bf[j][ks], acc[m + 4][j], 0, 0, 0);
    __builtin_amdgcn_s_setprio(0);
    __builtin_amdgcn_s_barrier();

    // ---- phase 3: no ds reads; stage (kt+2).A0 into SAME buf (reads of this
    // buf all retired by phase 2's end barrier); boundary wait, counted ----
    if (kt < 2) STAGE(bs, 0, kt + 2);
    __builtin_amdgcn_s_barrier();
    __builtin_amdgcn_s_setprio(1);
#pragma unroll
    for (int m = 0; m < 4; ++m)
#pragma unroll
      for (int j = 2; j < 4; ++j)
#pragma unroll
        for (int ks = 0; ks < 2; ++ks)
          acc[m + 4][j] = __builtin_amdgcn_mfma_f32_16x16x32_f16(af[m][ks], bf[j][ks], acc[m + 4][j], 0, 0, 0);
    __builtin_amdgcn_s_setprio(0);
    if (kt < 2) {
      asm volatile("s_waitcnt vmcnt(2)" ::: "memory");   // next K-tile landed, 1 half in flight
    } else if (kt == 2) {
      asm volatile("s_waitcnt vmcnt(0)" ::: "memory");   // final K-tile landed
    }
    __builtin_amdgcn_s_barrier();
  }
#undef STAGE

  // Epilogue: per-query-row max of dot * (1/kn) over each 128-key group
  float* cand = (float*)smem;  // [256 rows][4 wc-strips], overlays buf0 (dead)
  const int nb = nt * 256 + wc * 64;
  float rk[4];
  bool vld[4];
#pragma unroll
  for (int j = 0; j < 4; ++j) {
    const int c0 = nb + 16 * j;                 // 16 | NMEM -> frag-uniform
    vld[j] = (c0 < NMEM);
    rk[j] = vld[j] ? rkn[c0 + l16] : 0.f;
  }
#pragma unroll
  for (int i = 0; i < 8; ++i) {
#pragma unroll
    for (int r = 0; r < 4; ++r) {
      float m = -FLT_MAX;
#pragma unroll
      for (int j = 0; j < 4; ++j)
        if (vld[j]) m = fmaxf(m, acc[i][j][r] * rk[j]);
#pragma unroll
      for (int off = 1; off < 16; off <<= 1)
        m = fmaxf(m, __shfl_xor(m, off, 64));
      if (l16 == 0) cand[(wr * 128 + 16 * i + 4 * q16 + r) * 4 + wc] = m;
    }
  }
  __syncthreads();
  const int row = t & 255, g = t >> 8;          // two 128-key groups per tile
  const float v = fmaxf(cand[row * 4 + 2 * g], cand[row * 4 + 2 * g + 1]);
  bmaxT[(size_t)(2 * nt + g) * NQ + mt * 256 + row] = v;  // coalesced 1KB/group
}

// Pass 2: per query, find qualifying blocks, exact double rescore, gather values.
// fp16 screen error <= ~1e-3*||q|| in score units; margin 2.5e-3*||q|| > 2x bound.
__global__ __launch_bounds__(256) void rescore_gather(
    const float* __restrict__ q, const float* __restrict__ mem,
    const float* __restrict__ bmaxT, float* __restrict__ out) {
  __shared__ float red2[4];
  __shared__ int list[64];
  __shared__ int nlist;
  __shared__ double wb[4];
  __shared__ int wbi[4];
  __shared__ int widx;

  const int qi = blockIdx.x;
  const int t = threadIdx.x, w = t >> 6, lane = t & 63;
  const int r4 = lane >> 4, d16 = lane & 15;

  // this lane's 16 query dims, in registers once
  float4 q4[4];
#pragma unroll
  for (int c = 0; c < 4; ++c)
    q4[c] = *(const float4*)&q[(size_t)qi * 256 + d16 * 16 + c * 4];

  // ||q||: each dim covered by 4 lanes (r4 groups) -> wave sum = 4*||q||^2
  float ss = 0.f;
#pragma unroll
  for (int c = 0; c < 4; ++c)
    ss += q4[c].x * q4[c].x + q4[c].y * q4[c].y + q4[c].z * q4[c].z + q4[c].w * q4[c].w;
#pragma unroll
  for (int off = 32; off >= 1; off >>= 1) ss += __shfl_xor(ss, off, 64);
  const float qn = sqrtf(ss * 0.25f);
  const float margin = 2.5e-3f * qn;

  if (t == 0) nlist = 0;

  // global screened max over block maxima
  float gm = -FLT_MAX;
  for (int i = t; i < NTILES; i += 256) gm = fmaxf(gm, bmaxT[(size_t)i * NQ + qi]);
#pragma unroll
  for (int off = 32; off >= 1; off >>= 1) gm = fmaxf(gm, __shfl_xor(gm, off, 64));
  if (lane == 0) red2[w] = gm;
  __syncthreads();
  gm = fmaxf(fmaxf(red2[0], red2[1]), fmaxf(red2[2], red2[3]));
  const float thresh = gm - margin;

  for (int i = t; i < NTILES; i += 256)
    if (bmaxT[(size_t)i * NQ + qi] >= thresh) {
      int p = atomicAdd(&nlist, 1);
      if (p < 64) list[p] = i;
    }
  __syncthreads();
  const int nl = min(nlist, 64);

  double bestv = -1e300;
  int bestidx = 0x7fffffff;
  for (int c = 0; c < nl; ++c) {
    const int nt = list[c];
#pragma unroll 2
    for (int pass = 0; pass < 8; ++pass) {
      const int row = nt * 128 + w * 32 + pass * 4 + r4;
      double d = 0.0, s2 = 0.0;
      if (row < NMEM) {
#pragma unroll
        for (int c4 = 0; c4 < 4; ++c4) {
          const float4 kv = *(const float4*)&mem[(size_t)row * 512 + d16 * 16 + c4 * 4];
          d += (double)kv.x * q4[c4].x + (double)kv.y * q4[c4].y +
               (double)kv.z * q4[c4].z + (double)kv.w * q4[c4].w;
          s2 += (double)kv.x * kv.x + (double)kv.y * kv.y +
                (double)kv.z * kv.z + (double)kv.w * kv.w;
        }
      }
#pragma unroll
      for (int off = 1; off < 16; off <<= 1) {
        d += __shfl_xor(d, off, 64);
        s2 += __shfl_xor(s2, off, 64);
      }
      if (d16 == 0 && row < NMEM) {
        const double score = d / sqrt(s2 > 1e-300 ? s2 : 1e-300);
        if (score > bestv || (score == bestv && row < bestidx)) {
          bestv = score;
          bestidx = row;
        }
      }
    }
  }
  // cross-lane argmax (lanes with d16!=0 hold -1e300)
#pragma unroll
  for (int off = 1; off < 64; off <<= 1) {
    const double ov = __shfl_xor(bestv, off, 64);
    const int oi = __shfl_xor(bestidx, off, 64);
    if (ov > bestv || (ov == bestv && oi < bestidx)) {
      bestv = ov;
      bestidx = oi;
    }
  }
  if (lane == 0) { wb[w] = bestv; wbi[w] = bestidx; }
  __syncthreads();
  if (t == 0) {
    double bv = wb[0];
    int bi = wbi[0];
#pragma unroll
    for (int w2 = 1; w2 < 4; ++w2)
      if (wb[w2] > bv || (wb[w2] == bv && wbi[w2] < bi)) {
        bv = wb[w2];
        bi = wbi[w2];
      }
    widx = bi;
  }
  __syncthreads();
  out[(size_t)qi * 256 + t] = mem[(size_t)widx * 512 + 256 + t];
}

extern "C" void kernel_launch(void* const* d_in, const int* in_sizes, int n_in,
                              void* d_out, int out_size, void* d_ws, size_t ws_size,
                              hipStream_t stream) {
  const float* query = (const float*)d_in[0];
  const float* memory = (const float*)d_in[1];
  float* out = (float*)d_out;

  char* p = (char*)d_ws;
  unsigned short* qh = (unsigned short*)p; p += (size_t)NQ * MKEY * 2;
  unsigned short* kh = (unsigned short*)p; p += (size_t)NPAD * MKEY * 2;
  float* rkn = (float*)p; p += (size_t)NPAD * 4;
  float* bmaxT = (float*)p; p += (size_t)NQ * NTILES * 4;

  hipLaunchKernelGGL(convert, dim3(KEYBLOCKS + NQ * MKEY / 256), dim3(256), 0, stream,
                     query, memory, qh, kh, rkn);
  hipLaunchKernelGGL(gemm_screen, dim3(GRID2), dim3(512), 0, stream, qh, kh, rkn, bmaxT);
  hipLaunchKernelGGL(rescore_gather, dim3(NQ), dim3(256), 0, stream,
                     query, memory, bmaxT, out);
}